// Round 2
// baseline (711.504 us; speedup 1.0000x reference)
//
#include <hip/hip_runtime.h>

#define DIM 128
#define NGRAPH 512

// ---------- int32/int64 input hedge ----------
__device__ __forceinline__ int edge_at(const int* p, long long idx, int is64) {
  return is64 ? p[idx * 2] : p[(size_t)idx];
}

__global__ void k_detect64(const int* __restrict__ ei, int* __restrict__ flag) {
  if (threadIdx.x == 0 && blockIdx.x == 0) {
    int all0 = 1;
    for (int k = 0; k < 32; ++k)
      if (ei[2 * k + 1] != 0) all0 = 0;
    *flag = all0;  // 1 => buffers are int64, 0 => int32
  }
}

__global__ void k_zero(int* __restrict__ p, int n) {
  int i = blockIdx.x * 256 + threadIdx.x;
  if (i < n) p[i] = 0;
}

// ---------- degree histogram ----------
__global__ void k_count(const int* __restrict__ ei, int* __restrict__ cnt, int E,
                        const int* __restrict__ flag) {
  int is64 = *flag;
  for (int e = blockIdx.x * blockDim.x + threadIdx.x; e < E;
       e += gridDim.x * blockDim.x) {
    int d = edge_at(ei, (long long)E + e, is64);
    atomicAdd(&cnt[d], 1);
  }
}

__global__ void k_dinv(const int* __restrict__ cnt, float* __restrict__ dinv, int n) {
  int i = blockIdx.x * 256 + threadIdx.x;
  if (i < n) dinv[i] = rsqrtf((float)(cnt[i] + 1));  // +1 self loop
}

// ---------- exclusive scan (3 kernels) ----------
__global__ void k_scan1(const int* __restrict__ cnt, int* __restrict__ incl,
                        int* __restrict__ part, int n) {
  __shared__ int s[256];
  int t = threadIdx.x;
  int i = blockIdx.x * 256 + t;
  int v = (i < n) ? cnt[i] : 0;
  s[t] = v;
  __syncthreads();
  for (int off = 1; off < 256; off <<= 1) {
    int u = (t >= off) ? s[t - off] : 0;
    __syncthreads();
    s[t] += u;
    __syncthreads();
  }
  if (i < n) incl[i] = s[t];
  if (t == 255) part[blockIdx.x] = s[255];
}

__global__ void k_scan2(int* __restrict__ part, int nb) {
  __shared__ int s[512];
  int t = threadIdx.x;
  int v = (t < nb) ? part[t] : 0;
  s[t] = v;
  __syncthreads();
  for (int off = 1; off < 512; off <<= 1) {
    int u = (t >= off) ? s[t - off] : 0;
    __syncthreads();
    s[t] += u;
    __syncthreads();
  }
  if (t < nb) part[t] = s[t] - v;  // exclusive
}

__global__ void k_scan3(const int* __restrict__ incl, const int* __restrict__ cnt,
                        const int* __restrict__ part, int* __restrict__ row_off,
                        int* __restrict__ cursor, int n, int E) {
  int i = blockIdx.x * 256 + threadIdx.x;
  if (i < n) {
    int v = incl[i] - cnt[i] + part[blockIdx.x];  // global exclusive
    row_off[i] = v;
    cursor[i] = v;
  }
  if (i == 0) row_off[n] = E;
}

// ---------- CSR fill (src + precomputed norm) ----------
__global__ void k_fill(const int* __restrict__ ei, const float* __restrict__ dinv,
                       int* __restrict__ cursor, int* __restrict__ csr_src,
                       float* __restrict__ csr_nrm, int E, const int* __restrict__ flag) {
  int is64 = *flag;
  for (int e = blockIdx.x * blockDim.x + threadIdx.x; e < E;
       e += gridDim.x * blockDim.x) {
    int s = edge_at(ei, e, is64);
    int d = edge_at(ei, (long long)E + e, is64);
    int pos = atomicAdd(&cursor[d], 1);
    csr_src[pos] = s;
    csr_nrm[pos] = dinv[s] * dinv[d];
  }
}

// ---------- fp32 GEMM  C[M x 128] = A[M x 128] @ W[128 x 128] ----------
__global__ __launch_bounds__(256) void k_gemm128(const float* __restrict__ A,
                                                 const float* __restrict__ W,
                                                 float* __restrict__ C, int M) {
  __shared__ float sA[16][64];   // sA[kk][m] = A[m0+m][k0+kk]
  __shared__ float sB[16][128];  // sB[kk][c] = W[k0+kk][c]
  int tid = threadIdx.x;
  int m0 = blockIdx.x * 64;
  int tm = tid >> 5;   // 0..7  (8 rows each)
  int tc = tid & 31;   // 0..31 (4 cols each)
  float acc[8][4];
#pragma unroll
  for (int m = 0; m < 8; ++m)
#pragma unroll
    for (int c = 0; c < 4; ++c) acc[m][c] = 0.f;

  int lr = tid >> 2;           // 0..63 row for A-load
  int lk = (tid & 3) * 4;      // k quad
  int ar = m0 + lr; if (ar >= M) ar = M - 1;  // clamp (stores guarded)
  int br = tid >> 5;           // 0..7
  int bc = (tid & 31) * 4;

  for (int k0 = 0; k0 < 128; k0 += 16) {
    float4 va = *(const float4*)&A[(size_t)ar * 128 + k0 + lk];
    sA[lk + 0][lr] = va.x; sA[lk + 1][lr] = va.y;
    sA[lk + 2][lr] = va.z; sA[lk + 3][lr] = va.w;
    *(float4*)&sB[br][bc]     = *(const float4*)&W[(k0 + br) * 128 + bc];
    *(float4*)&sB[br + 8][bc] = *(const float4*)&W[(k0 + br + 8) * 128 + bc];
    __syncthreads();
#pragma unroll
    for (int kk = 0; kk < 16; ++kk) {
      float4 a0 = *(const float4*)&sA[kk][tm * 8];
      float4 a1 = *(const float4*)&sA[kk][tm * 8 + 4];
      float4 b  = *(const float4*)&sB[kk][tc * 4];
      float av[8] = {a0.x, a0.y, a0.z, a0.w, a1.x, a1.y, a1.z, a1.w};
      float bv[4] = {b.x, b.y, b.z, b.w};
#pragma unroll
      for (int m = 0; m < 8; ++m)
#pragma unroll
        for (int c = 0; c < 4; ++c) acc[m][c] += av[m] * bv[c];
    }
    __syncthreads();
  }
#pragma unroll
  for (int m = 0; m < 8; ++m) {
    int row = m0 + tm * 8 + m;
    if (row < M) {
      float4 v; v.x = acc[m][0]; v.y = acc[m][1]; v.z = acc[m][2]; v.w = acc[m][3];
      *(float4*)&C[(size_t)row * 128 + tc * 4] = v;
    }
  }
}

// ---------- aggregation: out[i] = sum_e nrm_e*xw[src_e] + dinv_i^2*xw[i] + b ----------
__global__ __launch_bounds__(64) void k_aggregate(
    const float* __restrict__ xw, const int* __restrict__ csr_src,
    const float* __restrict__ csr_nrm, const int* __restrict__ row_off,
    const float* __restrict__ dinv, const float* __restrict__ bias,
    float* __restrict__ out, int do_relu) {
  int i = blockIdx.x;           // one node per 64-lane wave
  int lane = threadIdx.x;       // 2 floats per lane (float2)
  int beg = row_off[i], end = row_off[i + 1];
  float di = dinv[i];
  const float2* base = (const float2*)xw;
  float2 self = base[(size_t)i * 64 + lane];
  float ax = self.x * di * di;
  float ay = self.y * di * di;
  int e = beg;
  for (; e + 4 <= end; e += 4) {
    int i0 = csr_src[e], i1 = csr_src[e + 1], i2 = csr_src[e + 2], i3 = csr_src[e + 3];
    float n0 = csr_nrm[e], n1 = csr_nrm[e + 1], n2 = csr_nrm[e + 2], n3 = csr_nrm[e + 3];
    float2 v0 = base[(size_t)i0 * 64 + lane];
    float2 v1 = base[(size_t)i1 * 64 + lane];
    float2 v2 = base[(size_t)i2 * 64 + lane];
    float2 v3 = base[(size_t)i3 * 64 + lane];
    ax += v0.x * n0; ay += v0.y * n0;
    ax += v1.x * n1; ay += v1.y * n1;
    ax += v2.x * n2; ay += v2.y * n2;
    ax += v3.x * n3; ay += v3.y * n3;
  }
  for (; e < end; ++e) {
    int i0 = csr_src[e]; float n0 = csr_nrm[e];
    float2 v0 = base[(size_t)i0 * 64 + lane];
    ax += v0.x * n0; ay += v0.y * n0;
  }
  float2 b = ((const float2*)bias)[lane];
  ax += b.x; ay += b.y;
  if (do_relu) { ax = fmaxf(ax, 0.f); ay = fmaxf(ay, 0.f); }
  float2 o; o.x = ax; o.y = ay;
  ((float2*)out)[(size_t)i * 64 + lane] = o;
}

// ---------- global mean pool + relu (batch is sorted) ----------
__device__ __forceinline__ int batch_at(const int* b, int i, int is64) {
  return is64 ? b[i * 2] : b[i];
}

__global__ __launch_bounds__(128) void k_pool(const float* __restrict__ h,
                                              const int* __restrict__ batch,
                                              float* __restrict__ g, int n,
                                              const int* __restrict__ flag) {
  int gid = blockIdx.x;
  int is64 = *flag;
  __shared__ int bounds[2];
  if (threadIdx.x < 2) {
    int target = gid + threadIdx.x;
    int lo = 0, hi = n;
    while (lo < hi) {
      int mid = (lo + hi) >> 1;
      if (batch_at(batch, mid, is64) < target) lo = mid + 1; else hi = mid;
    }
    bounds[threadIdx.x] = lo;
  }
  __syncthreads();
  int lo = bounds[0], hi = bounds[1];
  float s = 0.f;
  for (int r = lo; r < hi; ++r) s += h[(size_t)r * 128 + threadIdx.x];
  float c = (float)(hi - lo);
  float m = s / fmaxf(c, 1.0f);
  g[gid * 128 + threadIdx.x] = fmaxf(m, 0.f);  // relu fused
}

// ---------- final: out[512x32] = g @ Wl + bl ----------
__global__ __launch_bounds__(256) void k_final(const float* __restrict__ g,
                                               const float* __restrict__ Wl,
                                               const float* __restrict__ bl,
                                               float* __restrict__ out) {
  __shared__ float sW[128 * 32];
  for (int t = threadIdx.x; t < 128 * 32; t += 256) sW[t] = Wl[t];
  __syncthreads();
  int r = blockIdx.x * 8 + (threadIdx.x >> 5);
  int c = threadIdx.x & 31;
  const float* gr = &g[r * 128];
  float acc = bl[c];
#pragma unroll 4
  for (int k = 0; k < 128; ++k) acc += gr[k] * sW[k * 32 + c];
  out[r * 32 + c] = acc;
}

extern "C" void kernel_launch(void* const* d_in, const int* in_sizes, int n_in,
                              void* d_out, int out_size, void* d_ws, size_t ws_size,
                              hipStream_t stream) {
  const float* x   = (const float*)d_in[0];
  const int* ei    = (const int*)d_in[1];
  const int* batch = (const int*)d_in[2];
  const float* W1  = (const float*)d_in[3];
  const float* b1  = (const float*)d_in[4];
  const float* W2  = (const float*)d_in[5];
  const float* b2  = (const float*)d_in[6];
  const float* Wl  = (const float*)d_in[7];
  const float* bl  = (const float*)d_in[8];
  float* out = (float*)d_out;

  const int N = in_sizes[0] / DIM;   // 100000
  const int E = in_sizes[1] / 2;     // 1600000

  // workspace budget check: never write past ws_size (an undersized ws would
  // otherwise OOB-write and could kill the container rather than just failing)
  size_t need = 2 * (size_t)N * DIM * 4      // bufA, bufB
              + 3 * (size_t)N * 4            // cnt, cursor, dinv
              + (size_t)(N + 1) * 4          // row_off
              + 512 * 4 + 64                 // part + flag + pad
              + 2 * (size_t)E * 4            // csr_src, csr_nrm
              + (size_t)NGRAPH * DIM * 4;    // pooled
  if (ws_size < need) return;  // loud validation failure, no crash

  char* w = (char*)d_ws;
  float* bufA    = (float*)w; w += (size_t)N * DIM * 4;
  float* bufB    = (float*)w; w += (size_t)N * DIM * 4;
  int*   cnt     = (int*)w;   w += (size_t)N * 4;
  int*   row_off = (int*)w;   w += (size_t)(N + 1) * 4;
  int*   cursor  = (int*)w;   w += (size_t)N * 4;
  float* dinv    = (float*)w; w += (size_t)N * 4;
  int*   part    = (int*)w;   w += 512 * 4;
  int*   flag    = (int*)w;   w += 4;
  int*   csr_src = (int*)w;   w += (size_t)E * 4;
  float* csr_nrm = (float*)w; w += (size_t)E * 4;
  float* pooled  = (float*)w; w += (size_t)NGRAPH * DIM * 4;

  int nb = (N + 255) / 256;  // 391 <= 512

  k_detect64<<<1, 64, 0, stream>>>(ei, flag);
  k_zero<<<(N + 255) / 256, 256, 0, stream>>>(cnt, N);
  k_count<<<2048, 256, 0, stream>>>(ei, cnt, E, flag);
  k_dinv<<<(N + 255) / 256, 256, 0, stream>>>(cnt, dinv, N);
  k_scan1<<<nb, 256, 0, stream>>>(cnt, row_off, part, N);
  k_scan2<<<1, 512, 0, stream>>>(part, nb);
  k_scan3<<<nb, 256, 0, stream>>>(row_off, cnt, part, row_off, cursor, N, E);
  k_fill<<<2048, 256, 0, stream>>>(ei, dinv, cursor, csr_src, csr_nrm, E, flag);

  k_gemm128<<<(N + 63) / 64, 256, 0, stream>>>(x, W1, bufA, N);
  k_aggregate<<<N, 64, 0, stream>>>(bufA, csr_src, csr_nrm, row_off, dinv, b1, bufB, 1);
  k_gemm128<<<(N + 63) / 64, 256, 0, stream>>>(bufB, W2, bufA, N);
  k_aggregate<<<N, 64, 0, stream>>>(bufA, csr_src, csr_nrm, row_off, dinv, b2, bufB, 0);
  k_pool<<<NGRAPH, 128, 0, stream>>>(bufB, batch, pooled, N, flag);
  k_final<<<NGRAPH / 8, 256, 0, stream>>>(pooled, Wl, bl, out);
}

// Round 3
// 697.199 us; speedup vs baseline: 1.0205x; 1.0205x over previous
//
#include <hip/hip_runtime.h>

#define DIM 128
#define NGRAPH 512

// ---------- fused zero + int64-layout detect ----------
__global__ void k_zero_detect(int* __restrict__ p, int n, const int* __restrict__ ei,
                              int* __restrict__ flag) {
  int i = blockIdx.x * 256 + threadIdx.x;
  if (i < n) p[i] = 0;
  if (i == 0) {
    int all0 = 1;
    for (int k = 0; k < 32; ++k)
      if (ei[2 * k + 1] != 0) all0 = 0;
    *flag = all0;  // 1 => int64 buffers, 0 => int32
  }
}

// ---------- degree histogram (vectorized edge reads) ----------
__global__ void k_count(const int* __restrict__ ei, int* __restrict__ cnt, int E,
                        const int* __restrict__ flag) {
  int is64 = *flag;
  int half = E >> 1;  // E is even (1.6M); handle pairs
  if (is64) {
    const int4* dp = (const int4*)(ei + 2 * (size_t)E);
    for (int t = blockIdx.x * blockDim.x + threadIdx.x; t < half;
         t += gridDim.x * blockDim.x) {
      int4 d = dp[t];
      atomicAdd(&cnt[d.x], 1);
      atomicAdd(&cnt[d.z], 1);
    }
  } else {
    const int2* dp = (const int2*)(ei + (size_t)E);
    for (int t = blockIdx.x * blockDim.x + threadIdx.x; t < half;
         t += gridDim.x * blockDim.x) {
      int2 d = dp[t];
      atomicAdd(&cnt[d.x], 1);
      atomicAdd(&cnt[d.y], 1);
    }
  }
}

// ---------- exclusive scan (3 kernels) ----------
__global__ void k_scan1(const int* __restrict__ cnt, int* __restrict__ incl,
                        int* __restrict__ part, int n) {
  __shared__ int s[256];
  int t = threadIdx.x;
  int i = blockIdx.x * 256 + t;
  int v = (i < n) ? cnt[i] : 0;
  s[t] = v;
  __syncthreads();
  for (int off = 1; off < 256; off <<= 1) {
    int u = (t >= off) ? s[t - off] : 0;
    __syncthreads();
    s[t] += u;
    __syncthreads();
  }
  if (i < n) incl[i] = s[t];
  if (t == 255) part[blockIdx.x] = s[255];
}

__global__ void k_scan2(int* __restrict__ part, int nb) {
  __shared__ int s[512];
  int t = threadIdx.x;
  int v = (t < nb) ? part[t] : 0;
  s[t] = v;
  __syncthreads();
  for (int off = 1; off < 512; off <<= 1) {
    int u = (t >= off) ? s[t - off] : 0;
    __syncthreads();
    s[t] += u;
    __syncthreads();
  }
  if (t < nb) part[t] = s[t] - v;  // exclusive
}

// scan3 + fused dinv computation
__global__ void k_scan3(const int* __restrict__ incl, const int* __restrict__ cnt,
                        const int* __restrict__ part, int* __restrict__ row_off,
                        int* __restrict__ cursor, float* __restrict__ dinv,
                        int n, int E) {
  int i = blockIdx.x * 256 + threadIdx.x;
  if (i < n) {
    int v = incl[i] - cnt[i] + part[blockIdx.x];  // global exclusive
    row_off[i] = v;
    cursor[i] = v;
    dinv[i] = rsqrtf((float)(cnt[i] + 1));  // +1 self loop, deg>=1 always
  }
  if (i == 0) row_off[n] = E;
}

// ---------- CSR fill: src only (norm folded into GEMM epilogue) ----------
__global__ void k_fill(const int* __restrict__ ei, int* __restrict__ cursor,
                       int* __restrict__ csr_src, int E, const int* __restrict__ flag) {
  int is64 = *flag;
  int half = E >> 1;
  if (is64) {
    const int4* sp = (const int4*)ei;
    const int4* dp = (const int4*)(ei + 2 * (size_t)E);
    for (int t = blockIdx.x * blockDim.x + threadIdx.x; t < half;
         t += gridDim.x * blockDim.x) {
      int4 s = sp[t];
      int4 d = dp[t];
      int p0 = atomicAdd(&cursor[d.x], 1);
      csr_src[p0] = s.x;
      int p1 = atomicAdd(&cursor[d.z], 1);
      csr_src[p1] = s.z;
    }
  } else {
    const int2* sp = (const int2*)ei;
    const int2* dp = (const int2*)(ei + (size_t)E);
    for (int t = blockIdx.x * blockDim.x + threadIdx.x; t < half;
         t += gridDim.x * blockDim.x) {
      int2 s = sp[t];
      int2 d = dp[t];
      int p0 = atomicAdd(&cursor[d.x], 1);
      csr_src[p0] = s.x;
      int p1 = atomicAdd(&cursor[d.y], 1);
      csr_src[p1] = s.y;
    }
  }
}

// ---------- fp32 GEMM  C[r] = dinv[r] * (A[r] @ W),  A:[M x 128], W:[128 x 128] ----------
__global__ __launch_bounds__(256) void k_gemm128(const float* __restrict__ A,
                                                 const float* __restrict__ W,
                                                 const float* __restrict__ dinv,
                                                 float* __restrict__ C, int M) {
  __shared__ float sA[16][64];   // sA[kk][m] = A[m0+m][k0+kk]
  __shared__ float sB[16][128];  // sB[kk][c] = W[k0+kk][c]
  int tid = threadIdx.x;
  int m0 = blockIdx.x * 64;
  int tm = tid >> 5;   // 0..7  (8 rows each)
  int tc = tid & 31;   // 0..31 (4 cols each)
  float acc[8][4];
#pragma unroll
  for (int m = 0; m < 8; ++m)
#pragma unroll
    for (int c = 0; c < 4; ++c) acc[m][c] = 0.f;

  int lr = tid >> 2;           // 0..63 row for A-load
  int lk = (tid & 3) * 4;      // k quad
  int ar = m0 + lr; if (ar >= M) ar = M - 1;  // clamp (stores guarded)
  int br = tid >> 5;           // 0..7
  int bc = (tid & 31) * 4;

  for (int k0 = 0; k0 < 128; k0 += 16) {
    float4 va = *(const float4*)&A[(size_t)ar * 128 + k0 + lk];
    sA[lk + 0][lr] = va.x; sA[lk + 1][lr] = va.y;
    sA[lk + 2][lr] = va.z; sA[lk + 3][lr] = va.w;
    *(float4*)&sB[br][bc]     = *(const float4*)&W[(k0 + br) * 128 + bc];
    *(float4*)&sB[br + 8][bc] = *(const float4*)&W[(k0 + br + 8) * 128 + bc];
    __syncthreads();
#pragma unroll
    for (int kk = 0; kk < 16; ++kk) {
      float4 a0 = *(const float4*)&sA[kk][tm * 8];
      float4 a1 = *(const float4*)&sA[kk][tm * 8 + 4];
      float4 b  = *(const float4*)&sB[kk][tc * 4];
      float av[8] = {a0.x, a0.y, a0.z, a0.w, a1.x, a1.y, a1.z, a1.w};
      float bv[4] = {b.x, b.y, b.z, b.w};
#pragma unroll
      for (int m = 0; m < 8; ++m)
#pragma unroll
        for (int c = 0; c < 4; ++c) acc[m][c] += av[m] * bv[c];
    }
    __syncthreads();
  }
#pragma unroll
  for (int m = 0; m < 8; ++m) {
    int row = m0 + tm * 8 + m;
    if (row < M) {
      float dr = dinv[row];
      float4 v; v.x = acc[m][0] * dr; v.y = acc[m][1] * dr;
      v.z = acc[m][2] * dr; v.w = acc[m][3] * dr;
      *(float4*)&C[(size_t)row * 128 + tc * 4] = v;
    }
  }
}

// ---------- aggregation: out[i] = dinv_i*(sum_e y[src_e] + y[i]) + b ----------
// y rows are pre-scaled by dinv in the GEMM epilogue -> pure gather-add.
__global__ __launch_bounds__(256) void k_aggregate(
    const float* __restrict__ y, const int* __restrict__ csr_src,
    const int* __restrict__ row_off, const float* __restrict__ dinv,
    const float* __restrict__ bias, float* __restrict__ out, int do_relu, int N) {
  int node = blockIdx.x * 4 + (threadIdx.x >> 6);  // one node per 64-lane wave
  if (node >= N) return;
  int lane = threadIdx.x & 63;  // 2 floats per lane
  int beg = row_off[node], end = row_off[node + 1];
  float di = dinv[node];
  const float2* base = (const float2*)y;
  float2 self = base[(size_t)node * 64 + lane];
  float ax = self.x, ay = self.y;
  int e = beg;
  for (; e + 8 <= end; e += 8) {
    int s0 = csr_src[e + 0], s1 = csr_src[e + 1], s2 = csr_src[e + 2], s3 = csr_src[e + 3];
    int s4 = csr_src[e + 4], s5 = csr_src[e + 5], s6 = csr_src[e + 6], s7 = csr_src[e + 7];
    float2 v0 = base[(size_t)s0 * 64 + lane];
    float2 v1 = base[(size_t)s1 * 64 + lane];
    float2 v2 = base[(size_t)s2 * 64 + lane];
    float2 v3 = base[(size_t)s3 * 64 + lane];
    float2 v4 = base[(size_t)s4 * 64 + lane];
    float2 v5 = base[(size_t)s5 * 64 + lane];
    float2 v6 = base[(size_t)s6 * 64 + lane];
    float2 v7 = base[(size_t)s7 * 64 + lane];
    ax += v0.x; ay += v0.y;  ax += v1.x; ay += v1.y;
    ax += v2.x; ay += v2.y;  ax += v3.x; ay += v3.y;
    ax += v4.x; ay += v4.y;  ax += v5.x; ay += v5.y;
    ax += v6.x; ay += v6.y;  ax += v7.x; ay += v7.y;
  }
  for (; e < end; ++e) {
    int s0 = csr_src[e];
    float2 v0 = base[(size_t)s0 * 64 + lane];
    ax += v0.x; ay += v0.y;
  }
  float2 b = ((const float2*)bias)[lane];
  ax = di * ax + b.x;
  ay = di * ay + b.y;
  if (do_relu) { ax = fmaxf(ax, 0.f); ay = fmaxf(ay, 0.f); }
  float2 o; o.x = ax; o.y = ay;
  ((float2*)out)[(size_t)node * 64 + lane] = o;
}

// ---------- global mean pool + relu (batch is sorted) ----------
__device__ __forceinline__ int batch_at(const int* b, int i, int is64) {
  return is64 ? b[i * 2] : b[i];
}

__global__ __launch_bounds__(128) void k_pool(const float* __restrict__ h,
                                              const int* __restrict__ batch,
                                              float* __restrict__ g, int n,
                                              const int* __restrict__ flag) {
  int gid = blockIdx.x;
  int is64 = *flag;
  __shared__ int bounds[2];
  if (threadIdx.x < 2) {
    int target = gid + threadIdx.x;
    int lo = 0, hi = n;
    while (lo < hi) {
      int mid = (lo + hi) >> 1;
      if (batch_at(batch, mid, is64) < target) lo = mid + 1; else hi = mid;
    }
    bounds[threadIdx.x] = lo;
  }
  __syncthreads();
  int lo = bounds[0], hi = bounds[1];
  float s = 0.f;
  for (int r = lo; r < hi; ++r) s += h[(size_t)r * 128 + threadIdx.x];
  float c = (float)(hi - lo);
  float m = s / fmaxf(c, 1.0f);
  g[gid * 128 + threadIdx.x] = fmaxf(m, 0.f);  // relu fused
}

// ---------- final: out[512x32] = g @ Wl + bl ----------
__global__ __launch_bounds__(256) void k_final(const float* __restrict__ g,
                                               const float* __restrict__ Wl,
                                               const float* __restrict__ bl,
                                               float* __restrict__ out) {
  __shared__ float sW[128 * 32];
  for (int t = threadIdx.x; t < 128 * 32; t += 256) sW[t] = Wl[t];
  __syncthreads();
  int r = blockIdx.x * 8 + (threadIdx.x >> 5);
  int c = threadIdx.x & 31;
  const float* gr = &g[r * 128];
  float acc = bl[c];
#pragma unroll 4
  for (int k = 0; k < 128; ++k) acc += gr[k] * sW[k * 32 + c];
  out[r * 32 + c] = acc;
}

extern "C" void kernel_launch(void* const* d_in, const int* in_sizes, int n_in,
                              void* d_out, int out_size, void* d_ws, size_t ws_size,
                              hipStream_t stream) {
  const float* x   = (const float*)d_in[0];
  const int* ei    = (const int*)d_in[1];
  const int* batch = (const int*)d_in[2];
  const float* W1  = (const float*)d_in[3];
  const float* b1  = (const float*)d_in[4];
  const float* W2  = (const float*)d_in[5];
  const float* b2  = (const float*)d_in[6];
  const float* Wl  = (const float*)d_in[7];
  const float* bl  = (const float*)d_in[8];
  float* out = (float*)d_out;

  const int N = in_sizes[0] / DIM;   // 100000
  const int E = in_sizes[1] / 2;     // 1600000

  size_t need = 2 * (size_t)N * DIM * 4      // bufA, bufB
              + 3 * (size_t)N * 4            // cnt, cursor, dinv
              + (size_t)(N + 1) * 4          // row_off
              + 512 * 4 + 64                 // part + flag + pad
              + (size_t)E * 4                // csr_src
              + (size_t)NGRAPH * DIM * 4;    // pooled
  if (ws_size < need) return;  // refuse to OOB-write

  char* w = (char*)d_ws;
  float* bufA    = (float*)w; w += (size_t)N * DIM * 4;
  float* bufB    = (float*)w; w += (size_t)N * DIM * 4;
  int*   cnt     = (int*)w;   w += (size_t)N * 4;
  int*   row_off = (int*)w;   w += (size_t)(N + 1) * 4;
  int*   cursor  = (int*)w;   w += (size_t)N * 4;
  float* dinv    = (float*)w; w += (size_t)N * 4;
  int*   part    = (int*)w;   w += 512 * 4;
  int*   flag    = (int*)w;   w += 64;   // pad to 16B
  int*   csr_src = (int*)w;   w += (size_t)E * 4;
  float* pooled  = (float*)w; w += (size_t)NGRAPH * DIM * 4;

  int nb = (N + 255) / 256;  // 391 <= 512

  k_zero_detect<<<nb, 256, 0, stream>>>(cnt, N, ei, flag);
  k_count<<<1024, 256, 0, stream>>>(ei, cnt, E, flag);
  k_scan1<<<nb, 256, 0, stream>>>(cnt, row_off, part, N);
  k_scan2<<<1, 512, 0, stream>>>(part, nb);
  k_scan3<<<nb, 256, 0, stream>>>(row_off, cnt, part, row_off, cursor, dinv, N, E);
  k_fill<<<1024, 256, 0, stream>>>(ei, cursor, csr_src, E, flag);

  k_gemm128<<<(N + 63) / 64, 256, 0, stream>>>(x, W1, dinv, bufA, N);
  k_aggregate<<<(N + 3) / 4, 256, 0, stream>>>(bufA, csr_src, row_off, dinv, b1, bufB, 1, N);
  k_gemm128<<<(N + 63) / 64, 256, 0, stream>>>(bufB, W2, dinv, bufA, N);
  k_aggregate<<<(N + 3) / 4, 256, 0, stream>>>(bufA, csr_src, row_off, dinv, b2, bufB, 0, N);
  k_pool<<<NGRAPH, 128, 0, stream>>>(bufB, batch, pooled, N, flag);
  k_final<<<NGRAPH / 8, 256, 0, stream>>>(pooled, Wl, bl, out);
}

// Round 4
// 517.195 us; speedup vs baseline: 1.3757x; 1.3480x over previous
//
#include <hip/hip_runtime.h>
#include <hip/hip_fp16.h>

#define DIM 128
#define NGRAPH 512
#define BUCKET_SHIFT 9
#define BUCKET_NODES 512

// ---------- int32/int64 input hedge ----------
__device__ __forceinline__ int edge_at(const int* p, long long idx, int is64) {
  return is64 ? p[idx * 2] : p[(size_t)idx];
}

__global__ void k_detect(const int* __restrict__ ei, int* __restrict__ flag) {
  if (threadIdx.x == 0) {
    int all0 = 1;
    for (int k = 0; k < 32; ++k)
      if (ei[2 * k + 1] != 0) all0 = 0;
    *flag = all0;  // 1 => int64 buffers, 0 => int32
  }
}

// ---------- bucket histogram: bucket_count[dst>>9]++ over all edges ----------
__global__ __launch_bounds__(256) void k_bucket_hist(const int* __restrict__ ei, int E,
                                                     const int* __restrict__ flag,
                                                     int* __restrict__ bucket_count,
                                                     int nbuck) {
  __shared__ int h[256];
  int tid = threadIdx.x;
  h[tid] = 0;
  __syncthreads();
  int is64 = *flag;
  int half = E >> 1;
  if (is64) {
    const int4* dp = (const int4*)(ei + 2 * (size_t)E);
    for (int t = blockIdx.x * 256 + tid; t < half; t += gridDim.x * 256) {
      int4 d = dp[t];
      atomicAdd(&h[d.x >> BUCKET_SHIFT], 1);
      atomicAdd(&h[d.z >> BUCKET_SHIFT], 1);
    }
  } else {
    const int2* dp = (const int2*)(ei + (size_t)E);
    for (int t = blockIdx.x * 256 + tid; t < half; t += gridDim.x * 256) {
      int2 d = dp[t];
      atomicAdd(&h[d.x >> BUCKET_SHIFT], 1);
      atomicAdd(&h[d.y >> BUCKET_SHIFT], 1);
    }
  }
  __syncthreads();
  if (tid < nbuck && h[tid]) atomicAdd(&bucket_count[tid], h[tid]);
  if ((E & 1) && blockIdx.x == 0 && tid == 0) {
    int d = edge_at(ei, (long long)E + (E - 1), is64);
    atomicAdd(&bucket_count[d >> BUCKET_SHIFT], 1);
  }
}

// ---------- scan buckets (1 block, nbuck<=256) ----------
__global__ __launch_bounds__(256) void k_bucket_scan(const int* __restrict__ bucket_count,
                                                     int* __restrict__ bucket_off,
                                                     int* __restrict__ bucket_cursor,
                                                     int* __restrict__ row_off,
                                                     int nbuck, int N, int E) {
  __shared__ int s[256];
  int t = threadIdx.x;
  int v = (t < nbuck) ? bucket_count[t] : 0;
  s[t] = v;
  __syncthreads();
  for (int off = 1; off < 256; off <<= 1) {
    int u = (t >= off) ? s[t - off] : 0;
    __syncthreads();
    s[t] += u;
    __syncthreads();
  }
  int excl = s[t] - v;
  if (t < nbuck) { bucket_off[t] = excl; bucket_cursor[t] = excl; }
  if (t == 0) { bucket_off[nbuck] = E; row_off[N] = E; }
}

// ---------- scatter edges into bucket-grouped staging (per-block reservation) ----------
__global__ __launch_bounds__(256) void k_scatter(const int* __restrict__ ei, int E,
                                                 const int* __restrict__ flag,
                                                 int* __restrict__ bucket_cursor,
                                                 int2* __restrict__ staging, int nbuck) {
  __shared__ int h[256];
  __shared__ int basebuf[256];
  int tid = threadIdx.x;
  int half = E >> 1;
  int ppb = (half + gridDim.x - 1) / gridDim.x;
  int lo = blockIdx.x * ppb;
  int hi = min(lo + ppb, half);
  h[tid] = 0;
  __syncthreads();
  int is64 = *flag;
  // phase 1: local bucket counts
  if (is64) {
    const int4* dp = (const int4*)(ei + 2 * (size_t)E);
    for (int t = lo + tid; t < hi; t += 256) {
      int4 d = dp[t];
      atomicAdd(&h[d.x >> BUCKET_SHIFT], 1);
      atomicAdd(&h[d.z >> BUCKET_SHIFT], 1);
    }
  } else {
    const int2* dp = (const int2*)(ei + (size_t)E);
    for (int t = lo + tid; t < hi; t += 256) {
      int2 d = dp[t];
      atomicAdd(&h[d.x >> BUCKET_SHIFT], 1);
      atomicAdd(&h[d.y >> BUCKET_SHIFT], 1);
    }
  }
  __syncthreads();
  // reservation: one global atomic per (block,bucket)
  if (tid < nbuck) {
    int c = h[tid];
    if (c) basebuf[tid] = atomicAdd(&bucket_cursor[tid], c);
    h[tid] = 0;  // reuse as local cursor
  }
  __syncthreads();
  // phase 2: scatter
  if (is64) {
    const int4* sp = (const int4*)ei;
    const int4* dp = (const int4*)(ei + 2 * (size_t)E);
    for (int t = lo + tid; t < hi; t += 256) {
      int4 sv = sp[t];
      int4 dv = dp[t];
      int b0 = dv.x >> BUCKET_SHIFT;
      int l0 = atomicAdd(&h[b0], 1);
      staging[basebuf[b0] + l0] = make_int2(sv.x, dv.x);
      int b1 = dv.z >> BUCKET_SHIFT;
      int l1 = atomicAdd(&h[b1], 1);
      staging[basebuf[b1] + l1] = make_int2(sv.z, dv.z);
    }
  } else {
    const int2* sp = (const int2*)ei;
    const int2* dp = (const int2*)(ei + (size_t)E);
    for (int t = lo + tid; t < hi; t += 256) {
      int2 sv = sp[t];
      int2 dv = dp[t];
      int b0 = dv.x >> BUCKET_SHIFT;
      int l0 = atomicAdd(&h[b0], 1);
      staging[basebuf[b0] + l0] = make_int2(sv.x, dv.x);
      int b1 = dv.y >> BUCKET_SHIFT;
      int l1 = atomicAdd(&h[b1], 1);
      staging[basebuf[b1] + l1] = make_int2(sv.y, dv.y);
    }
  }
  if ((E & 1) && blockIdx.x == 0 && tid == 0) {
    int s0 = edge_at(ei, E - 1, is64);
    int d0 = edge_at(ei, (long long)E + (E - 1), is64);
    int pos = atomicAdd(&bucket_cursor[d0 >> BUCKET_SHIFT], 1);
    staging[pos] = make_int2(s0, d0);
  }
}

// ---------- per-bucket: node histogram + scan + CSR scatter + row_off + dinv ----------
__global__ __launch_bounds__(256) void k_csr_build(const int2* __restrict__ staging,
                                                   const int* __restrict__ bucket_off,
                                                   int* __restrict__ row_off,
                                                   float* __restrict__ dinv,
                                                   int* __restrict__ csr_src, int N) {
  __shared__ int cnt_s[BUCKET_NODES];
  __shared__ int s[256];
  int tid = threadIdx.x;
  int b = blockIdx.x;
  int base = b << BUCKET_SHIFT;
  cnt_s[tid] = 0;
  cnt_s[tid + 256] = 0;
  __syncthreads();
  int start = bucket_off[b], end = bucket_off[b + 1];
  for (int i = start + tid; i < end; i += 256) {
    int2 e = staging[i];
    atomicAdd(&cnt_s[e.y - base], 1);
  }
  __syncthreads();
  int a0 = cnt_s[2 * tid], a1 = cnt_s[2 * tid + 1];
  int ps = a0 + a1;
  s[tid] = ps;
  __syncthreads();
  for (int off = 1; off < 256; off <<= 1) {
    int u = (tid >= off) ? s[tid - off] : 0;
    __syncthreads();
    s[tid] += u;
    __syncthreads();
  }
  int excl = s[tid] - ps;  // exclusive over node pairs
  int r0 = start + excl;
  int r1 = r0 + a0;
  cnt_s[2 * tid] = r0;       // absolute cursors
  cnt_s[2 * tid + 1] = r1;
  int n0 = base + 2 * tid, n1 = n0 + 1;
  if (n0 < N) { row_off[n0] = r0; dinv[n0] = rsqrtf((float)(a0 + 1)); }
  if (n1 < N) { row_off[n1] = r1; dinv[n1] = rsqrtf((float)(a1 + 1)); }
  __syncthreads();
  for (int i = start + tid; i < end; i += 256) {
    int2 e = staging[i];
    int pos = atomicAdd(&cnt_s[e.y - base], 1);
    csr_src[pos] = e.x;
  }
}

// ---------- fp32 GEMM, epilogue Y[r] = fp16( dinv[r] * (A[r] @ W) ) ----------
__global__ __launch_bounds__(256) void k_gemm128(const float* __restrict__ A,
                                                 const float* __restrict__ W,
                                                 const float* __restrict__ dinv,
                                                 __half* __restrict__ Y, int M) {
  __shared__ float sA[16][64];   // sA[kk][m] = A[m0+m][k0+kk]
  __shared__ float sB[16][128];  // sB[kk][c] = W[k0+kk][c]
  int tid = threadIdx.x;
  int m0 = blockIdx.x * 64;
  int tm = tid >> 5;   // 0..7
  int tc = tid & 31;   // 0..31
  float acc[8][4];
#pragma unroll
  for (int m = 0; m < 8; ++m)
#pragma unroll
    for (int c = 0; c < 4; ++c) acc[m][c] = 0.f;

  int lr = tid >> 2;
  int lk = (tid & 3) * 4;
  int ar = m0 + lr; if (ar >= M) ar = M - 1;
  int br = tid >> 5;
  int bc = (tid & 31) * 4;

  for (int k0 = 0; k0 < 128; k0 += 16) {
    float4 va = *(const float4*)&A[(size_t)ar * 128 + k0 + lk];
    sA[lk + 0][lr] = va.x; sA[lk + 1][lr] = va.y;
    sA[lk + 2][lr] = va.z; sA[lk + 3][lr] = va.w;
    *(float4*)&sB[br][bc]     = *(const float4*)&W[(k0 + br) * 128 + bc];
    *(float4*)&sB[br + 8][bc] = *(const float4*)&W[(k0 + br + 8) * 128 + bc];
    __syncthreads();
#pragma unroll
    for (int kk = 0; kk < 16; ++kk) {
      float4 a0 = *(const float4*)&sA[kk][tm * 8];
      float4 a1 = *(const float4*)&sA[kk][tm * 8 + 4];
      float4 bq = *(const float4*)&sB[kk][tc * 4];
      float av[8] = {a0.x, a0.y, a0.z, a0.w, a1.x, a1.y, a1.z, a1.w};
      float bv[4] = {bq.x, bq.y, bq.z, bq.w};
#pragma unroll
      for (int m = 0; m < 8; ++m)
#pragma unroll
        for (int c = 0; c < 4; ++c) acc[m][c] += av[m] * bv[c];
    }
    __syncthreads();
  }
#pragma unroll
  for (int m = 0; m < 8; ++m) {
    int row = m0 + tm * 8 + m;
    if (row < M) {
      float dr = dinv[row];
      __half2 h0 = __floats2half2_rn(acc[m][0] * dr, acc[m][1] * dr);
      __half2 h1 = __floats2half2_rn(acc[m][2] * dr, acc[m][3] * dr);
      __half2* yp = (__half2*)&Y[(size_t)row * 128 + tc * 4];
      yp[0] = h0; yp[1] = h1;
    }
  }
}

// ---------- aggregation: out[i] = dinv_i*(sum_e y[src_e] + y[i]) + b (y fp16) ----------
__global__ __launch_bounds__(256) void k_aggregate(
    const __half* __restrict__ y, const int* __restrict__ csr_src,
    const int* __restrict__ row_off, const float* __restrict__ dinv,
    const float* __restrict__ bias, float* __restrict__ out, int do_relu, int N) {
  int node = blockIdx.x * 4 + (threadIdx.x >> 6);
  if (node >= N) return;
  int lane = threadIdx.x & 63;  // 2 halfs per lane
  int beg = row_off[node], end = row_off[node + 1];
  float di = dinv[node];
  const __half2* base = (const __half2*)y;
  __half2 sv = base[(size_t)node * 64 + lane];
  float ax = __low2float(sv), ay = __high2float(sv);
  int e = beg;
  for (; e + 8 <= end; e += 8) {
    int s0 = csr_src[e + 0], s1 = csr_src[e + 1], s2 = csr_src[e + 2], s3 = csr_src[e + 3];
    int s4 = csr_src[e + 4], s5 = csr_src[e + 5], s6 = csr_src[e + 6], s7 = csr_src[e + 7];
    __half2 v0 = base[(size_t)s0 * 64 + lane];
    __half2 v1 = base[(size_t)s1 * 64 + lane];
    __half2 v2 = base[(size_t)s2 * 64 + lane];
    __half2 v3 = base[(size_t)s3 * 64 + lane];
    __half2 v4 = base[(size_t)s4 * 64 + lane];
    __half2 v5 = base[(size_t)s5 * 64 + lane];
    __half2 v6 = base[(size_t)s6 * 64 + lane];
    __half2 v7 = base[(size_t)s7 * 64 + lane];
    ax += __low2float(v0); ay += __high2float(v0);
    ax += __low2float(v1); ay += __high2float(v1);
    ax += __low2float(v2); ay += __high2float(v2);
    ax += __low2float(v3); ay += __high2float(v3);
    ax += __low2float(v4); ay += __high2float(v4);
    ax += __low2float(v5); ay += __high2float(v5);
    ax += __low2float(v6); ay += __high2float(v6);
    ax += __low2float(v7); ay += __high2float(v7);
  }
  for (; e < end; ++e) {
    __half2 v0 = base[(size_t)csr_src[e] * 64 + lane];
    ax += __low2float(v0); ay += __high2float(v0);
  }
  float2 b = ((const float2*)bias)[lane];
  ax = di * ax + b.x;
  ay = di * ay + b.y;
  if (do_relu) { ax = fmaxf(ax, 0.f); ay = fmaxf(ay, 0.f); }
  float2 o; o.x = ax; o.y = ay;
  ((float2*)out)[(size_t)node * 64 + lane] = o;
}

// ---------- global mean pool + relu (batch is sorted) ----------
__device__ __forceinline__ int batch_at(const int* b, int i, int is64) {
  return is64 ? b[i * 2] : b[i];
}

__global__ __launch_bounds__(128) void k_pool(const float* __restrict__ h,
                                              const int* __restrict__ batch,
                                              float* __restrict__ g, int n,
                                              const int* __restrict__ flag) {
  int gid = blockIdx.x;
  int is64 = *flag;
  __shared__ int bounds[2];
  if (threadIdx.x < 2) {
    int target = gid + threadIdx.x;
    int lo = 0, hi = n;
    while (lo < hi) {
      int mid = (lo + hi) >> 1;
      if (batch_at(batch, mid, is64) < target) lo = mid + 1; else hi = mid;
    }
    bounds[threadIdx.x] = lo;
  }
  __syncthreads();
  int lo = bounds[0], hi = bounds[1];
  float s = 0.f;
  for (int r = lo; r < hi; ++r) s += h[(size_t)r * 128 + threadIdx.x];
  float c = (float)(hi - lo);
  float m = s / fmaxf(c, 1.0f);
  g[gid * 128 + threadIdx.x] = fmaxf(m, 0.f);  // relu fused
}

// ---------- final: out[512x32] = g @ Wl + bl ----------
__global__ __launch_bounds__(256) void k_final(const float* __restrict__ g,
                                               const float* __restrict__ Wl,
                                               const float* __restrict__ bl,
                                               float* __restrict__ out) {
  __shared__ float sW[128 * 32];
  for (int t = threadIdx.x; t < 128 * 32; t += 256) sW[t] = Wl[t];
  __syncthreads();
  int r = blockIdx.x * 8 + (threadIdx.x >> 5);
  int c = threadIdx.x & 31;
  const float* gr = &g[r * 128];
  float acc = bl[c];
#pragma unroll 4
  for (int k = 0; k < 128; ++k) acc += gr[k] * sW[k * 32 + c];
  out[r * 32 + c] = acc;
}

extern "C" void kernel_launch(void* const* d_in, const int* in_sizes, int n_in,
                              void* d_out, int out_size, void* d_ws, size_t ws_size,
                              hipStream_t stream) {
  const float* x   = (const float*)d_in[0];
  const int* ei    = (const int*)d_in[1];
  const int* batch = (const int*)d_in[2];
  const float* W1  = (const float*)d_in[3];
  const float* b1  = (const float*)d_in[4];
  const float* W2  = (const float*)d_in[5];
  const float* b2  = (const float*)d_in[6];
  const float* Wl  = (const float*)d_in[7];
  const float* bl  = (const float*)d_in[8];
  float* out = (float*)d_out;

  const int N = in_sizes[0] / DIM;   // 100000
  const int E = in_sizes[1] / 2;     // 1600000
  const int NBUCK = (N + BUCKET_NODES - 1) >> BUCKET_SHIFT;  // 196 (<=256)

  size_t need = (size_t)N * DIM * 2          // bufY (fp16)
              + (size_t)N * DIM * 4          // bufH (fp32)
              + (size_t)E * 4                // csr_src
              + (size_t)(N + 1) * 4          // row_off
              + (size_t)N * 4                // dinv
              + 3 * 1088 + 64                // bucket arrays + flag
              + (size_t)NGRAPH * DIM * 4;    // pooled
  if (ws_size < need) return;  // refuse to OOB-write

  char* w = (char*)d_ws;
  __half* bufY  = (__half*)w; w += (size_t)N * DIM * 2;
  float* bufH   = (float*)w;  w += (size_t)N * DIM * 4;
  int* csr_src  = (int*)w;    w += (size_t)E * 4;
  int* row_off  = (int*)w;    w += (size_t)(N + 1) * 4;
  float* dinv   = (float*)w;  w += (size_t)N * 4;
  int* bucket_count  = (int*)w; w += 1088;
  int* bucket_off    = (int*)w; w += 1088;
  int* bucket_cursor = (int*)w; w += 1088;
  int* flag     = (int*)w;    w += 64;
  float* pooled = (float*)w;  w += (size_t)NGRAPH * DIM * 4;
  // staging overlays bufY+bufH (dead until gemm1, which runs after csr_build)
  int2* staging = (int2*)bufY;

  hipMemsetAsync(bucket_count, 0, 1088, stream);
  k_detect<<<1, 64, 0, stream>>>(ei, flag);
  k_bucket_hist<<<1024, 256, 0, stream>>>(ei, E, flag, bucket_count, NBUCK);
  k_bucket_scan<<<1, 256, 0, stream>>>(bucket_count, bucket_off, bucket_cursor,
                                       row_off, NBUCK, N, E);
  k_scatter<<<1024, 256, 0, stream>>>(ei, E, flag, bucket_cursor, staging, NBUCK);
  k_csr_build<<<NBUCK, 256, 0, stream>>>(staging, bucket_off, row_off, dinv, csr_src, N);

  k_gemm128<<<(N + 63) / 64, 256, 0, stream>>>(x, W1, dinv, bufY, N);
  k_aggregate<<<(N + 3) / 4, 256, 0, stream>>>(bufY, csr_src, row_off, dinv, b1, bufH, 1, N);
  k_gemm128<<<(N + 63) / 64, 256, 0, stream>>>(bufH, W2, dinv, bufY, N);
  k_aggregate<<<(N + 3) / 4, 256, 0, stream>>>(bufY, csr_src, row_off, dinv, b2, bufH, 0, N);
  k_pool<<<NGRAPH, 128, 0, stream>>>(bufH, batch, pooled, N, flag);
  k_final<<<NGRAPH / 8, 256, 0, stream>>>(pooled, Wl, bl, out);
}

// Round 5
// 459.178 us; speedup vs baseline: 1.5495x; 1.1263x over previous
//
#include <hip/hip_runtime.h>
#include <hip/hip_fp16.h>

#define DIM 128
#define NGRAPH 512
#define BUCKET_SHIFT 9
#define BUCKET_NODES 512

typedef _Float16 half8 __attribute__((ext_vector_type(8)));
typedef float floatx4 __attribute__((ext_vector_type(4)));

// ---------- per-block int64-layout detection (ei values random -> unambiguous) ----------
__device__ __forceinline__ int detect64(const int* __restrict__ ei) {
  int all0 = 1;
#pragma unroll
  for (int k = 0; k < 32; ++k) all0 &= (ei[2 * k + 1] == 0);
  return all0;
}

__device__ __forceinline__ int edge_at(const int* p, long long idx, int is64) {
  return is64 ? p[idx * 2] : p[(size_t)idx];
}

// ---------- bucket histogram ----------
__global__ __launch_bounds__(256) void k_bucket_hist(const int* __restrict__ ei, int E,
                                                     int* __restrict__ bucket_count,
                                                     int nbuck) {
  __shared__ int h[256];
  int tid = threadIdx.x;
  h[tid] = 0;
  __syncthreads();
  int is64 = detect64(ei);
  int half = E >> 1;
  if (is64) {
    const int4* dp = (const int4*)(ei + 2 * (size_t)E);
    for (int t = blockIdx.x * 256 + tid; t < half; t += gridDim.x * 256) {
      int4 d = dp[t];
      atomicAdd(&h[d.x >> BUCKET_SHIFT], 1);
      atomicAdd(&h[d.z >> BUCKET_SHIFT], 1);
    }
  } else {
    const int2* dp = (const int2*)(ei + (size_t)E);
    for (int t = blockIdx.x * 256 + tid; t < half; t += gridDim.x * 256) {
      int2 d = dp[t];
      atomicAdd(&h[d.x >> BUCKET_SHIFT], 1);
      atomicAdd(&h[d.y >> BUCKET_SHIFT], 1);
    }
  }
  __syncthreads();
  if (tid < nbuck && h[tid]) atomicAdd(&bucket_count[tid], h[tid]);
  if ((E & 1) && blockIdx.x == 0 && tid == 0) {
    int d = edge_at(ei, (long long)E + (E - 1), is64);
    atomicAdd(&bucket_count[d >> BUCKET_SHIFT], 1);
  }
}

// ---------- scan buckets (1 block) ----------
__global__ __launch_bounds__(256) void k_bucket_scan(const int* __restrict__ bucket_count,
                                                     int* __restrict__ bucket_off,
                                                     int* __restrict__ bucket_cursor,
                                                     int* __restrict__ row_off,
                                                     int nbuck, int N, int E) {
  __shared__ int s[256];
  int t = threadIdx.x;
  int v = (t < nbuck) ? bucket_count[t] : 0;
  s[t] = v;
  __syncthreads();
  for (int off = 1; off < 256; off <<= 1) {
    int u = (t >= off) ? s[t - off] : 0;
    __syncthreads();
    s[t] += u;
    __syncthreads();
  }
  int excl = s[t] - v;
  if (t < nbuck) { bucket_off[t] = excl; bucket_cursor[t] = excl; }
  if (t == 0) { bucket_off[nbuck] = E; row_off[N] = E; }
}

// ---------- scatter edges into bucket-grouped staging ----------
__global__ __launch_bounds__(256) void k_scatter(const int* __restrict__ ei, int E,
                                                 int* __restrict__ flag,
                                                 int* __restrict__ bucket_cursor,
                                                 int2* __restrict__ staging, int nbuck) {
  __shared__ int h[256];
  __shared__ int basebuf[256];
  int tid = threadIdx.x;
  int half = E >> 1;
  int ppb = (half + gridDim.x - 1) / gridDim.x;
  int lo = blockIdx.x * ppb;
  int hi = min(lo + ppb, half);
  h[tid] = 0;
  __syncthreads();
  int is64 = detect64(ei);
  if (blockIdx.x == 0 && tid == 0) *flag = is64;  // published for k_pool_final
  // phase 1: local bucket counts
  if (is64) {
    const int4* dp = (const int4*)(ei + 2 * (size_t)E);
    for (int t = lo + tid; t < hi; t += 256) {
      int4 d = dp[t];
      atomicAdd(&h[d.x >> BUCKET_SHIFT], 1);
      atomicAdd(&h[d.z >> BUCKET_SHIFT], 1);
    }
  } else {
    const int2* dp = (const int2*)(ei + (size_t)E);
    for (int t = lo + tid; t < hi; t += 256) {
      int2 d = dp[t];
      atomicAdd(&h[d.x >> BUCKET_SHIFT], 1);
      atomicAdd(&h[d.y >> BUCKET_SHIFT], 1);
    }
  }
  __syncthreads();
  if (tid < nbuck) {
    int c = h[tid];
    if (c) basebuf[tid] = atomicAdd(&bucket_cursor[tid], c);
    h[tid] = 0;  // reuse as local cursor
  }
  __syncthreads();
  // phase 2: scatter
  if (is64) {
    const int4* sp = (const int4*)ei;
    const int4* dp = (const int4*)(ei + 2 * (size_t)E);
    for (int t = lo + tid; t < hi; t += 256) {
      int4 sv = sp[t];
      int4 dv = dp[t];
      int b0 = dv.x >> BUCKET_SHIFT;
      int l0 = atomicAdd(&h[b0], 1);
      staging[basebuf[b0] + l0] = make_int2(sv.x, dv.x);
      int b1 = dv.z >> BUCKET_SHIFT;
      int l1 = atomicAdd(&h[b1], 1);
      staging[basebuf[b1] + l1] = make_int2(sv.z, dv.z);
    }
  } else {
    const int2* sp = (const int2*)ei;
    const int2* dp = (const int2*)(ei + (size_t)E);
    for (int t = lo + tid; t < hi; t += 256) {
      int2 sv = sp[t];
      int2 dv = dp[t];
      int b0 = dv.x >> BUCKET_SHIFT;
      int l0 = atomicAdd(&h[b0], 1);
      staging[basebuf[b0] + l0] = make_int2(sv.x, dv.x);
      int b1 = dv.y >> BUCKET_SHIFT;
      int l1 = atomicAdd(&h[b1], 1);
      staging[basebuf[b1] + l1] = make_int2(sv.y, dv.y);
    }
  }
  if ((E & 1) && blockIdx.x == 0 && tid == 0) {
    int s0 = edge_at(ei, E - 1, is64);
    int d0 = edge_at(ei, (long long)E + (E - 1), is64);
    int pos = atomicAdd(&bucket_cursor[d0 >> BUCKET_SHIFT], 1);
    staging[pos] = make_int2(s0, d0);
  }
}

// ---------- per-bucket CSR build ----------
__global__ __launch_bounds__(256) void k_csr_build(const int2* __restrict__ staging,
                                                   const int* __restrict__ bucket_off,
                                                   int* __restrict__ row_off,
                                                   float* __restrict__ dinv,
                                                   int* __restrict__ csr_src, int N) {
  __shared__ int cnt_s[BUCKET_NODES];
  __shared__ int s[256];
  int tid = threadIdx.x;
  int b = blockIdx.x;
  int base = b << BUCKET_SHIFT;
  cnt_s[tid] = 0;
  cnt_s[tid + 256] = 0;
  __syncthreads();
  int start = bucket_off[b], end = bucket_off[b + 1];
  for (int i = start + tid; i < end; i += 256) {
    int2 e = staging[i];
    atomicAdd(&cnt_s[e.y - base], 1);
  }
  __syncthreads();
  int a0 = cnt_s[2 * tid], a1 = cnt_s[2 * tid + 1];
  int ps = a0 + a1;
  s[tid] = ps;
  __syncthreads();
  for (int off = 1; off < 256; off <<= 1) {
    int u = (tid >= off) ? s[tid - off] : 0;
    __syncthreads();
    s[tid] += u;
    __syncthreads();
  }
  int excl = s[tid] - ps;
  int r0 = start + excl;
  int r1 = r0 + a0;
  cnt_s[2 * tid] = r0;
  cnt_s[2 * tid + 1] = r1;
  int n0 = base + 2 * tid, n1 = n0 + 1;
  if (n0 < N) { row_off[n0] = r0; dinv[n0] = rsqrtf((float)(a0 + 1)); }
  if (n1 < N) { row_off[n1] = r1; dinv[n1] = rsqrtf((float)(a1 + 1)); }
  __syncthreads();
  for (int i = start + tid; i < end; i += 256) {
    int2 e = staging[i];
    int pos = atomicAdd(&cnt_s[e.y - base], 1);
    csr_src[pos] = e.x;
  }
}

// ---------- MFMA split-fp16 GEMM: Y = fp16( dinv .* (A @ W) ), fp32-accurate ----------
// 3-term Ootomo: a_hi*w_hi + a_lo*w_hi + a_hi*w_lo  (error ~1e-6 rel)
// frag layouts (gfx950 16x16x32): A lane l: row=l&15, k=(l>>4)*8+j
//                                 B lane l: col=l&15, k=(l>>4)*8+j
//                                 D lane l reg r: row=(l>>4)*4+r, col=l&15
__global__ __launch_bounds__(256) void k_gemm_mfma(
    const float* __restrict__ A, const float* __restrict__ W,
    const float* __restrict__ dinv, __half* __restrict__ Y, int M) {
  __shared__ _Float16 WH[16384];          // [s][c][lane][8] : 32 KB
  __shared__ _Float16 WL[16384];          // residuals      : 32 KB
  __shared__ _Float16 OT[4][16 * 128];    // per-wave out tile: 16 KB
  int tid = threadIdx.x;

  // stage W fragments (hi + lo), once per block; W is L2-hot
  for (int idx = tid; idx < 2048; idx += 256) {
    int l = idx & 63, c = (idx >> 6) & 7, s = idx >> 9;
    int kbase = s * 32 + ((l >> 4) << 3);
    int col = c * 16 + (l & 15);
#pragma unroll
    for (int j = 0; j < 8; ++j) {
      float w = W[(kbase + j) * 128 + col];
      _Float16 hh = (_Float16)w;
      WH[idx * 8 + j] = hh;
      WL[idx * 8 + j] = (_Float16)(w - (float)hh);
    }
  }
  __syncthreads();

  int wid = tid >> 6, l = tid & 63;
  int row0 = blockIdx.x * 64 + wid * 16;
  int arow = row0 + (l & 15);
  if (arow >= M) arow = M - 1;  // clamp; stores guarded

  floatx4 acc[8];
#pragma unroll
  for (int c = 0; c < 8; ++c) acc[c] = (floatx4){0.f, 0.f, 0.f, 0.f};

#pragma unroll
  for (int s = 0; s < 4; ++s) {
    const float* ap = &A[(size_t)arow * 128 + s * 32 + ((l >> 4) << 3)];
    float4 f0 = *(const float4*)ap;
    float4 f1 = *(const float4*)(ap + 4);
    float fv[8] = {f0.x, f0.y, f0.z, f0.w, f1.x, f1.y, f1.z, f1.w};
    half8 ah, alo;
#pragma unroll
    for (int j = 0; j < 8; ++j) {
      _Float16 hh = (_Float16)fv[j];
      ah[j] = hh;
      alo[j] = (_Float16)(fv[j] - (float)hh);
    }
#pragma unroll
    for (int c = 0; c < 8; ++c) {
      int fi = ((s * 8 + c) * 64 + l) * 8;
      half8 bh = *(half8*)&WH[fi];
      half8 bl8 = *(half8*)&WL[fi];
      acc[c] = __builtin_amdgcn_mfma_f32_16x16x32_f16(ah, bh, acc[c], 0, 0, 0);
      acc[c] = __builtin_amdgcn_mfma_f32_16x16x32_f16(alo, bh, acc[c], 0, 0, 0);
      acc[c] = __builtin_amdgcn_mfma_f32_16x16x32_f16(ah, bl8, acc[c], 0, 0, 0);
    }
  }

  // epilogue: scale by dinv, fp16, LDS transpose, coalesced store
  _Float16* ot = &OT[wid][0];
  int lrb = (l >> 4) * 4;
  float dv[4];
#pragma unroll
  for (int r = 0; r < 4; ++r) {
    int gr = row0 + lrb + r;
    dv[r] = (gr < M) ? dinv[gr] : 0.f;
  }
#pragma unroll
  for (int c = 0; c < 8; ++c)
#pragma unroll
    for (int r = 0; r < 4; ++r)
      ot[(lrb + r) * 128 + c * 16 + (l & 15)] = (_Float16)(acc[c][r] * dv[r]);
  const float4* otf = (const float4*)ot;  // 256 float4 = 16 rows x 256 B
#pragma unroll
  for (int q = 0; q < 4; ++q) {
    int idx = q * 64 + l;
    int lrow = idx >> 4;
    int coff = (idx & 15) * 8;
    int grow = row0 + lrow;
    if (grow < M) *(float4*)&Y[(size_t)grow * 128 + coff] = otf[idx];
  }
}

// ---------- aggregation: out[i] = dinv_i*(sum y[src] + y[i]) + b, y fp16 ----------
// block = 4 consecutive nodes -> their CSR ranges are contiguous: LDS-stage indices
__global__ __launch_bounds__(256) void k_aggregate(
    const __half* __restrict__ y, const int* __restrict__ csr_src,
    const int* __restrict__ row_off, const float* __restrict__ dinv,
    const float* __restrict__ bias, float* __restrict__ out, int do_relu, int N) {
  __shared__ int sidx[1024];
  int tid = threadIdx.x;
  int n0 = blockIdx.x * 4;
  int lastn = min(n0 + 4, N);
  int blockBeg = row_off[n0];
  int blockEnd = row_off[lastn];
  int len = blockEnd - blockBeg;
  int nload = min(len, 1024);
  for (int t = tid; t < nload; t += 256) sidx[t] = csr_src[blockBeg + t];
  __syncthreads();
  int node = n0 + (tid >> 6);
  if (node >= N) return;
  int lane = tid & 63;
  int beg = row_off[node], end = row_off[node + 1];
  float di = dinv[node];
  const __half2* base = (const __half2*)y;
  __half2 sv = base[(size_t)node * 64 + lane];
  float ax = __low2float(sv), ay = __high2float(sv);
  int e = beg;
  if (len <= nload) {  // fast path: all indices in LDS (always, for deg<=1024/4)
    for (; e + 8 <= end; e += 8) {
      int idx[8];
#pragma unroll
      for (int j = 0; j < 8; ++j) idx[j] = sidx[e - blockBeg + j];
      __half2 v[8];
#pragma unroll
      for (int j = 0; j < 8; ++j) v[j] = base[(size_t)idx[j] * 64 + lane];
#pragma unroll
      for (int j = 0; j < 8; ++j) { ax += __low2float(v[j]); ay += __high2float(v[j]); }
    }
    for (; e < end; ++e) {
      __half2 v0 = base[(size_t)sidx[e - blockBeg] * 64 + lane];
      ax += __low2float(v0); ay += __high2float(v0);
    }
  } else {  // paranoia fallback
    for (; e < end; ++e) {
      __half2 v0 = base[(size_t)csr_src[e] * 64 + lane];
      ax += __low2float(v0); ay += __high2float(v0);
    }
  }
  float2 b = ((const float2*)bias)[lane];
  ax = di * ax + b.x;
  ay = di * ay + b.y;
  if (do_relu) { ax = fmaxf(ax, 0.f); ay = fmaxf(ay, 0.f); }
  float2 o; o.x = ax; o.y = ay;
  ((float2*)out)[(size_t)node * 64 + lane] = o;
}

// ---------- fused mean-pool + relu + final GEMM (block per graph) ----------
__global__ __launch_bounds__(128) void k_pool_final(
    const float* __restrict__ h, const int* __restrict__ batch,
    const float* __restrict__ Wl, const float* __restrict__ bl,
    float* __restrict__ out, int n, const int* __restrict__ flag) {
  __shared__ float sW[128 * 32];
  __shared__ float sg[128];
  __shared__ int bounds[2];
  int tid = threadIdx.x;
  int gid = blockIdx.x;
  for (int t = tid; t < 128 * 32; t += 128) sW[t] = Wl[t];
  int is64 = *flag;
  if (tid < 2) {
    int target = gid + tid;
    int lo = 0, hi = n;
    while (lo < hi) {
      int mid = (lo + hi) >> 1;
      int bv = is64 ? batch[2 * mid] : batch[mid];
      if (bv < target) lo = mid + 1; else hi = mid;
    }
    bounds[tid] = lo;
  }
  __syncthreads();
  int lo = bounds[0], hi = bounds[1];
  float s = 0.f;
  for (int r = lo; r < hi; ++r) s += h[(size_t)r * 128 + tid];
  sg[tid] = fmaxf(s / fmaxf((float)(hi - lo), 1.f), 0.f);
  __syncthreads();
  if (tid < 32) {
    float acc = bl[tid];
#pragma unroll 8
    for (int k = 0; k < 128; ++k) acc += sg[k] * sW[k * 32 + tid];
    out[gid * 32 + tid] = acc;
  }
}

extern "C" void kernel_launch(void* const* d_in, const int* in_sizes, int n_in,
                              void* d_out, int out_size, void* d_ws, size_t ws_size,
                              hipStream_t stream) {
  const float* x   = (const float*)d_in[0];
  const int* ei    = (const int*)d_in[1];
  const int* batch = (const int*)d_in[2];
  const float* W1  = (const float*)d_in[3];
  const float* b1  = (const float*)d_in[4];
  const float* W2  = (const float*)d_in[5];
  const float* b2  = (const float*)d_in[6];
  const float* Wl  = (const float*)d_in[7];
  const float* bl  = (const float*)d_in[8];
  float* out = (float*)d_out;

  const int N = in_sizes[0] / DIM;   // 100000
  const int E = in_sizes[1] / 2;     // 1600000
  const int NBUCK = (N + BUCKET_NODES - 1) >> BUCKET_SHIFT;  // 196

  size_t need = (size_t)N * DIM * 2 + (size_t)N * DIM * 4 + (size_t)E * 4
              + (size_t)(N + 1) * 4 + (size_t)N * 4 + 3 * 1088 + 64;
  if (ws_size < need) return;

  char* w = (char*)d_ws;
  __half* bufY  = (__half*)w; w += (size_t)N * DIM * 2;
  float* bufH   = (float*)w;  w += (size_t)N * DIM * 4;
  int* csr_src  = (int*)w;    w += (size_t)E * 4;
  int* row_off  = (int*)w;    w += (size_t)(N + 1) * 4;
  float* dinv   = (float*)w;  w += (size_t)N * 4;
  int* bucket_count  = (int*)w; w += 1088;
  int* bucket_off    = (int*)w; w += 1088;
  int* bucket_cursor = (int*)w; w += 1088;
  int* flag     = (int*)w;    w += 64;
  // staging overlays bufY+bufH (dead until gemm1, which runs after csr_build)
  int2* staging = (int2*)bufY;

  hipMemsetAsync(bucket_count, 0, 1088, stream);
  k_bucket_hist<<<1024, 256, 0, stream>>>(ei, E, bucket_count, NBUCK);
  k_bucket_scan<<<1, 256, 0, stream>>>(bucket_count, bucket_off, bucket_cursor,
                                       row_off, NBUCK, N, E);
  k_scatter<<<1024, 256, 0, stream>>>(ei, E, flag, bucket_cursor, staging, NBUCK);
  k_csr_build<<<NBUCK, 256, 0, stream>>>(staging, bucket_off, row_off, dinv, csr_src, N);

  k_gemm_mfma<<<(N + 63) / 64, 256, 0, stream>>>(x, W1, dinv, bufY, N);
  k_aggregate<<<(N + 3) / 4, 256, 0, stream>>>(bufY, csr_src, row_off, dinv, b1, bufH, 1, N);
  k_gemm_mfma<<<(N + 63) / 64, 256, 0, stream>>>(bufH, W2, dinv, bufY, N);
  k_aggregate<<<(N + 3) / 4, 256, 0, stream>>>(bufY, csr_src, row_off, dinv, b2, bufH, 0, N);
  k_pool_final<<<NGRAPH, 128, 0, stream>>>(bufH, batch, Wl, bl, out, N, flag);
}

// Round 6
// 441.096 us; speedup vs baseline: 1.6130x; 1.0410x over previous
//
#include <hip/hip_runtime.h>
#include <hip/hip_fp16.h>

#define DIM 128
#define NGRAPH 512
#define BUCKET_SHIFT 9
#define BUCKET_NODES 512

typedef _Float16 half8 __attribute__((ext_vector_type(8)));
typedef float floatx4 __attribute__((ext_vector_type(4)));

// ---------- per-block int64-layout detection (ei values random -> unambiguous) ----------
__device__ __forceinline__ int detect64(const int* __restrict__ ei) {
  int all0 = 1;
#pragma unroll
  for (int k = 0; k < 32; ++k) all0 &= (ei[2 * k + 1] == 0);
  return all0;
}

__device__ __forceinline__ int edge_at(const int* p, long long idx, int is64) {
  return is64 ? p[idx * 2] : p[(size_t)idx];
}

// ---------- bucket histogram ----------
__global__ __launch_bounds__(256) void k_bucket_hist(const int* __restrict__ ei, int E,
                                                     int* __restrict__ bucket_count,
                                                     int nbuck) {
  __shared__ int h[256];
  int tid = threadIdx.x;
  h[tid] = 0;
  __syncthreads();
  int is64 = detect64(ei);
  int half = E >> 1;
  if (is64) {
    const int4* dp = (const int4*)(ei + 2 * (size_t)E);
    for (int t = blockIdx.x * 256 + tid; t < half; t += gridDim.x * 256) {
      int4 d = dp[t];
      atomicAdd(&h[d.x >> BUCKET_SHIFT], 1);
      atomicAdd(&h[d.z >> BUCKET_SHIFT], 1);
    }
  } else {
    const int2* dp = (const int2*)(ei + (size_t)E);
    for (int t = blockIdx.x * 256 + tid; t < half; t += gridDim.x * 256) {
      int2 d = dp[t];
      atomicAdd(&h[d.x >> BUCKET_SHIFT], 1);
      atomicAdd(&h[d.y >> BUCKET_SHIFT], 1);
    }
  }
  __syncthreads();
  if (tid < nbuck && h[tid]) atomicAdd(&bucket_count[tid], h[tid]);
  if ((E & 1) && blockIdx.x == 0 && tid == 0) {
    int d = edge_at(ei, (long long)E + (E - 1), is64);
    atomicAdd(&bucket_count[d >> BUCKET_SHIFT], 1);
  }
}

// ---------- scan buckets (1 block) ----------
__global__ __launch_bounds__(256) void k_bucket_scan(const int* __restrict__ bucket_count,
                                                     int* __restrict__ bucket_off,
                                                     int* __restrict__ bucket_cursor,
                                                     int* __restrict__ row_off,
                                                     int nbuck, int N, int E) {
  __shared__ int s[256];
  int t = threadIdx.x;
  int v = (t < nbuck) ? bucket_count[t] : 0;
  s[t] = v;
  __syncthreads();
  for (int off = 1; off < 256; off <<= 1) {
    int u = (t >= off) ? s[t - off] : 0;
    __syncthreads();
    s[t] += u;
    __syncthreads();
  }
  int excl = s[t] - v;
  if (t < nbuck) { bucket_off[t] = excl; bucket_cursor[t] = excl; }
  if (t == 0) { bucket_off[nbuck] = E; row_off[N] = E; }
}

// ---------- scatter edges into bucket-grouped staging ----------
__global__ __launch_bounds__(256) void k_scatter(const int* __restrict__ ei, int E,
                                                 int* __restrict__ flag,
                                                 int* __restrict__ bucket_cursor,
                                                 int2* __restrict__ staging, int nbuck) {
  __shared__ int h[256];
  __shared__ int basebuf[256];
  int tid = threadIdx.x;
  int half = E >> 1;
  int ppb = (half + gridDim.x - 1) / gridDim.x;
  int lo = blockIdx.x * ppb;
  int hi = min(lo + ppb, half);
  h[tid] = 0;
  __syncthreads();
  int is64 = detect64(ei);
  if (blockIdx.x == 0 && tid == 0) *flag = is64;  // published for k_pool_partial
  // phase 1: local bucket counts
  if (is64) {
    const int4* dp = (const int4*)(ei + 2 * (size_t)E);
    for (int t = lo + tid; t < hi; t += 256) {
      int4 d = dp[t];
      atomicAdd(&h[d.x >> BUCKET_SHIFT], 1);
      atomicAdd(&h[d.z >> BUCKET_SHIFT], 1);
    }
  } else {
    const int2* dp = (const int2*)(ei + (size_t)E);
    for (int t = lo + tid; t < hi; t += 256) {
      int2 d = dp[t];
      atomicAdd(&h[d.x >> BUCKET_SHIFT], 1);
      atomicAdd(&h[d.y >> BUCKET_SHIFT], 1);
    }
  }
  __syncthreads();
  if (tid < nbuck) {
    int c = h[tid];
    if (c) basebuf[tid] = atomicAdd(&bucket_cursor[tid], c);
    h[tid] = 0;  // reuse as local cursor
  }
  __syncthreads();
  // phase 2: scatter
  if (is64) {
    const int4* sp = (const int4*)ei;
    const int4* dp = (const int4*)(ei + 2 * (size_t)E);
    for (int t = lo + tid; t < hi; t += 256) {
      int4 sv = sp[t];
      int4 dv = dp[t];
      int b0 = dv.x >> BUCKET_SHIFT;
      int l0 = atomicAdd(&h[b0], 1);
      staging[basebuf[b0] + l0] = make_int2(sv.x, dv.x);
      int b1 = dv.z >> BUCKET_SHIFT;
      int l1 = atomicAdd(&h[b1], 1);
      staging[basebuf[b1] + l1] = make_int2(sv.z, dv.z);
    }
  } else {
    const int2* sp = (const int2*)ei;
    const int2* dp = (const int2*)(ei + (size_t)E);
    for (int t = lo + tid; t < hi; t += 256) {
      int2 sv = sp[t];
      int2 dv = dp[t];
      int b0 = dv.x >> BUCKET_SHIFT;
      int l0 = atomicAdd(&h[b0], 1);
      staging[basebuf[b0] + l0] = make_int2(sv.x, dv.x);
      int b1 = dv.y >> BUCKET_SHIFT;
      int l1 = atomicAdd(&h[b1], 1);
      staging[basebuf[b1] + l1] = make_int2(sv.y, dv.y);
    }
  }
  if ((E & 1) && blockIdx.x == 0 && tid == 0) {
    int s0 = edge_at(ei, E - 1, is64);
    int d0 = edge_at(ei, (long long)E + (E - 1), is64);
    int pos = atomicAdd(&bucket_cursor[d0 >> BUCKET_SHIFT], 1);
    staging[pos] = make_int2(s0, d0);
  }
}

// ---------- per-bucket CSR build ----------
__global__ __launch_bounds__(256) void k_csr_build(const int2* __restrict__ staging,
                                                   const int* __restrict__ bucket_off,
                                                   int* __restrict__ row_off,
                                                   float* __restrict__ dinv,
                                                   int* __restrict__ csr_src, int N) {
  __shared__ int cnt_s[BUCKET_NODES];
  __shared__ int s[256];
  int tid = threadIdx.x;
  int b = blockIdx.x;
  int base = b << BUCKET_SHIFT;
  cnt_s[tid] = 0;
  cnt_s[tid + 256] = 0;
  __syncthreads();
  int start = bucket_off[b], end = bucket_off[b + 1];
  for (int i = start + tid; i < end; i += 256) {
    int2 e = staging[i];
    atomicAdd(&cnt_s[e.y - base], 1);
  }
  __syncthreads();
  int a0 = cnt_s[2 * tid], a1 = cnt_s[2 * tid + 1];
  int ps = a0 + a1;
  s[tid] = ps;
  __syncthreads();
  for (int off = 1; off < 256; off <<= 1) {
    int u = (tid >= off) ? s[tid - off] : 0;
    __syncthreads();
    s[tid] += u;
    __syncthreads();
  }
  int excl = s[tid] - ps;
  int r0 = start + excl;
  int r1 = r0 + a0;
  cnt_s[2 * tid] = r0;
  cnt_s[2 * tid + 1] = r1;
  int n0 = base + 2 * tid, n1 = n0 + 1;
  if (n0 < N) { row_off[n0] = r0; dinv[n0] = rsqrtf((float)(a0 + 1)); }
  if (n1 < N) { row_off[n1] = r1; dinv[n1] = rsqrtf((float)(a1 + 1)); }
  __syncthreads();
  for (int i = start + tid; i < end; i += 256) {
    int2 e = staging[i];
    int pos = atomicAdd(&cnt_s[e.y - base], 1);
    csr_src[pos] = e.x;
  }
}

// ---------- MFMA split-fp16 GEMM: Y = fp16( dinv .* (A @ W) ), fp32-accurate ----------
__global__ __launch_bounds__(256) void k_gemm_mfma(
    const float* __restrict__ A, const float* __restrict__ W,
    const float* __restrict__ dinv, __half* __restrict__ Y, int M) {
  __shared__ _Float16 WH[16384];          // [s][c][lane][8] : 32 KB
  __shared__ _Float16 WL[16384];          // residuals      : 32 KB
  __shared__ _Float16 OT[4][16 * 128];    // per-wave out tile: 16 KB
  int tid = threadIdx.x;

  for (int idx = tid; idx < 2048; idx += 256) {
    int l = idx & 63, c = (idx >> 6) & 7, s = idx >> 9;
    int kbase = s * 32 + ((l >> 4) << 3);
    int col = c * 16 + (l & 15);
#pragma unroll
    for (int j = 0; j < 8; ++j) {
      float w = W[(kbase + j) * 128 + col];
      _Float16 hh = (_Float16)w;
      WH[idx * 8 + j] = hh;
      WL[idx * 8 + j] = (_Float16)(w - (float)hh);
    }
  }
  __syncthreads();

  int wid = tid >> 6, l = tid & 63;
  int row0 = blockIdx.x * 64 + wid * 16;
  int arow = row0 + (l & 15);
  if (arow >= M) arow = M - 1;

  floatx4 acc[8];
#pragma unroll
  for (int c = 0; c < 8; ++c) acc[c] = (floatx4){0.f, 0.f, 0.f, 0.f};

#pragma unroll
  for (int s = 0; s < 4; ++s) {
    const float* ap = &A[(size_t)arow * 128 + s * 32 + ((l >> 4) << 3)];
    float4 f0 = *(const float4*)ap;
    float4 f1 = *(const float4*)(ap + 4);
    float fv[8] = {f0.x, f0.y, f0.z, f0.w, f1.x, f1.y, f1.z, f1.w};
    half8 ah, alo;
#pragma unroll
    for (int j = 0; j < 8; ++j) {
      _Float16 hh = (_Float16)fv[j];
      ah[j] = hh;
      alo[j] = (_Float16)(fv[j] - (float)hh);
    }
#pragma unroll
    for (int c = 0; c < 8; ++c) {
      int fi = ((s * 8 + c) * 64 + l) * 8;
      half8 bh = *(half8*)&WH[fi];
      half8 bl8 = *(half8*)&WL[fi];
      acc[c] = __builtin_amdgcn_mfma_f32_16x16x32_f16(ah, bh, acc[c], 0, 0, 0);
      acc[c] = __builtin_amdgcn_mfma_f32_16x16x32_f16(alo, bh, acc[c], 0, 0, 0);
      acc[c] = __builtin_amdgcn_mfma_f32_16x16x32_f16(ah, bl8, acc[c], 0, 0, 0);
    }
  }

  _Float16* ot = &OT[wid][0];
  int lrb = (l >> 4) * 4;
  float dv[4];
#pragma unroll
  for (int r = 0; r < 4; ++r) {
    int gr = row0 + lrb + r;
    dv[r] = (gr < M) ? dinv[gr] : 0.f;
  }
#pragma unroll
  for (int c = 0; c < 8; ++c)
#pragma unroll
    for (int r = 0; r < 4; ++r)
      ot[(lrb + r) * 128 + c * 16 + (l & 15)] = (_Float16)(acc[c][r] * dv[r]);
  const float4* otf = (const float4*)ot;
#pragma unroll
  for (int q = 0; q < 4; ++q) {
    int idx = q * 64 + l;
    int lrow = idx >> 4;
    int coff = (idx & 15) * 8;
    int grow = row0 + lrow;
    if (grow < M) *(float4*)&Y[(size_t)grow * 128 + coff] = otf[idx];
  }
}

// ---------- aggregation: out[i] = dinv_i*(sum y[src] + y[i]) + b, y fp16 ----------
__global__ __launch_bounds__(256) void k_aggregate(
    const __half* __restrict__ y, const int* __restrict__ csr_src,
    const int* __restrict__ row_off, const float* __restrict__ dinv,
    const float* __restrict__ bias, float* __restrict__ out, int do_relu, int N) {
  __shared__ int sidx[1024];
  int tid = threadIdx.x;
  int n0 = blockIdx.x * 4;
  int lastn = min(n0 + 4, N);
  int blockBeg = row_off[n0];
  int blockEnd = row_off[lastn];
  int len = blockEnd - blockBeg;
  int nload = min(len, 1024);
  for (int t = tid; t < nload; t += 256) sidx[t] = csr_src[blockBeg + t];
  __syncthreads();
  int node = n0 + (tid >> 6);
  if (node >= N) return;
  int lane = tid & 63;
  int beg = row_off[node], end = row_off[node + 1];
  float di = dinv[node];
  const __half2* base = (const __half2*)y;
  __half2 sv = base[(size_t)node * 64 + lane];
  float ax = __low2float(sv), ay = __high2float(sv);
  int e = beg;
  if (len <= nload) {
    for (; e + 8 <= end; e += 8) {
      int idx[8];
#pragma unroll
      for (int j = 0; j < 8; ++j) idx[j] = sidx[e - blockBeg + j];
      __half2 v[8];
#pragma unroll
      for (int j = 0; j < 8; ++j) v[j] = base[(size_t)idx[j] * 64 + lane];
#pragma unroll
      for (int j = 0; j < 8; ++j) { ax += __low2float(v[j]); ay += __high2float(v[j]); }
    }
    for (; e < end; ++e) {
      __half2 v0 = base[(size_t)sidx[e - blockBeg] * 64 + lane];
      ax += __low2float(v0); ay += __high2float(v0);
    }
  } else {
    for (; e < end; ++e) {
      __half2 v0 = base[(size_t)csr_src[e] * 64 + lane];
      ax += __low2float(v0); ay += __high2float(v0);
    }
  }
  float2 b = ((const float2*)bias)[lane];
  ax = di * ax + b.x;
  ay = di * ay + b.y;
  if (do_relu) { ax = fmaxf(ax, 0.f); ay = fmaxf(ay, 0.f); }
  float2 o; o.x = ax; o.y = ay;
  ((float2*)out)[(size_t)node * 64 + lane] = o;
}

// ---------- parallel mean-pool partial: atomics into pooled[512][128] ----------
// block = 128 threads (one col each) x 128 consecutive nodes; batch sorted ->
// few graph runs per block; flush acc at run boundaries only.
__global__ __launch_bounds__(128) void k_pool_partial(
    const float* __restrict__ h, const int* __restrict__ batch,
    float* __restrict__ pooled, int* __restrict__ pcnt, int n,
    const int* __restrict__ flag) {
  __shared__ int sbatch[128];
  int tid = threadIdx.x;
  int n0 = blockIdx.x * 128;
  int n1 = min(n0 + 128, n);
  int cnt = n1 - n0;
  int is64 = *flag;
  if (tid < cnt) sbatch[tid] = is64 ? batch[2 * (n0 + tid)] : batch[n0 + tid];
  __syncthreads();
  float acc = 0.f;
  int gcur = sbatch[0];
  int runlen = 0;
  for (int r = 0; r < cnt; ++r) {
    int g = sbatch[r];
    if (g != gcur) {
      atomicAdd(&pooled[(size_t)gcur * 128 + tid], acc);
      if (tid == 0) atomicAdd(&pcnt[gcur], runlen);
      acc = 0.f; runlen = 0; gcur = g;
    }
    acc += h[(size_t)(n0 + r) * 128 + tid];
    ++runlen;
  }
  atomicAdd(&pooled[(size_t)gcur * 128 + tid], acc);
  if (tid == 0) atomicAdd(&pcnt[gcur], runlen);
}

// ---------- finish: mean + relu + [512x128]@[128x32] + bl ----------
__global__ __launch_bounds__(256) void k_final2(
    const float* __restrict__ pooled, const int* __restrict__ pcnt,
    const float* __restrict__ Wl, const float* __restrict__ bl,
    float* __restrict__ out) {
  __shared__ float sW[128 * 32];
  __shared__ float sg[8][128];
  int tid = threadIdx.x;
  for (int t = tid; t < 128 * 32; t += 256) sW[t] = Wl[t];
  int r = blockIdx.x * 8 + (tid >> 5);  // graph id
  int c = tid & 31;
  float inv = 1.f / fmaxf((float)pcnt[r], 1.f);
  // each of the 32 lanes in this row-group loads 4 cols
#pragma unroll
  for (int q = 0; q < 4; ++q)
    sg[tid >> 5][c * 4 + q] = fmaxf(pooled[(size_t)r * 128 + c * 4 + q] * inv, 0.f);
  __syncthreads();
  const float* g = sg[tid >> 5];
  float acc = bl[c];
#pragma unroll 8
  for (int k = 0; k < 128; ++k) acc += g[k] * sW[k * 32 + c];
  out[r * 32 + c] = acc;
}

extern "C" void kernel_launch(void* const* d_in, const int* in_sizes, int n_in,
                              void* d_out, int out_size, void* d_ws, size_t ws_size,
                              hipStream_t stream) {
  const float* x   = (const float*)d_in[0];
  const int* ei    = (const int*)d_in[1];
  const int* batch = (const int*)d_in[2];
  const float* W1  = (const float*)d_in[3];
  const float* b1  = (const float*)d_in[4];
  const float* W2  = (const float*)d_in[5];
  const float* b2  = (const float*)d_in[6];
  const float* Wl  = (const float*)d_in[7];
  const float* bl  = (const float*)d_in[8];
  float* out = (float*)d_out;

  const int N = in_sizes[0] / DIM;   // 100000
  const int E = in_sizes[1] / 2;     // 1600000
  const int NBUCK = (N + BUCKET_NODES - 1) >> BUCKET_SHIFT;  // 196

  size_t need = (size_t)N * DIM * 2 + (size_t)N * DIM * 4 + (size_t)E * 4
              + (size_t)(N + 1) * 4 + (size_t)N * 4 + 3 * 1088 + 64
              + (size_t)NGRAPH * DIM * 4 + NGRAPH * 4;
  if (ws_size < need) return;

  char* w = (char*)d_ws;
  __half* bufY  = (__half*)w; w += (size_t)N * DIM * 2;
  float* bufH   = (float*)w;  w += (size_t)N * DIM * 4;
  int* csr_src  = (int*)w;    w += (size_t)E * 4;
  int* row_off  = (int*)w;    w += (size_t)(N + 1) * 4;
  float* dinv   = (float*)w;  w += (size_t)N * 4;
  int* bucket_count  = (int*)w; w += 1088;
  int* bucket_off    = (int*)w; w += 1088;
  int* bucket_cursor = (int*)w; w += 1088;
  int* flag     = (int*)w;    w += 64;
  float* pooled = (float*)w;  w += (size_t)NGRAPH * DIM * 4;
  int* pcnt     = (int*)w;    w += NGRAPH * 4;
  // staging overlays bufY+bufH (dead until gemm1, which runs after csr_build)
  int2* staging = (int2*)bufY;

  hipMemsetAsync(bucket_count, 0, 1088, stream);
  hipMemsetAsync(pooled, 0, (size_t)NGRAPH * DIM * 4 + NGRAPH * 4, stream);
  k_bucket_hist<<<1024, 256, 0, stream>>>(ei, E, bucket_count, NBUCK);
  k_bucket_scan<<<1, 256, 0, stream>>>(bucket_count, bucket_off, bucket_cursor,
                                       row_off, NBUCK, N, E);
  k_scatter<<<1024, 256, 0, stream>>>(ei, E, flag, bucket_cursor, staging, NBUCK);
  k_csr_build<<<NBUCK, 256, 0, stream>>>(staging, bucket_off, row_off, dinv, csr_src, N);

  k_gemm_mfma<<<(N + 63) / 64, 256, 0, stream>>>(x, W1, dinv, bufY, N);
  k_aggregate<<<(N + 3) / 4, 256, 0, stream>>>(bufY, csr_src, row_off, dinv, b1, bufH, 1, N);
  k_gemm_mfma<<<(N + 63) / 64, 256, 0, stream>>>(bufH, W2, dinv, bufY, N);
  k_aggregate<<<(N + 3) / 4, 256, 0, stream>>>(bufY, csr_src, row_off, dinv, b2, bufH, 0, N);
  k_pool_partial<<<(N + 127) / 128, 128, 0, stream>>>(bufH, batch, pooled, pcnt, N, flag);
  k_final2<<<NGRAPH / 8, 256, 0, stream>>>(pooled, pcnt, Wl, bl, out);
}